// Round 4
// baseline (1084.711 us; speedup 1.0000x reference)
//
#include <hip/hip_runtime.h>
#include <hip/hip_cooperative_groups.h>
#include <hip/hip_bf16.h>
#include <stdint.h>

namespace cg = cooperative_groups;

#define B_ 16
#define N_ 16384
#define D_ 128
#define E_ 65536
#define NTILES (B_ * (N_ / 64))  // 4096 tiles of 64 rows

typedef __attribute__((ext_vector_type(8))) __bf16 bf16x8;
typedef __attribute__((ext_vector_type(4))) float f32x4;

__device__ __forceinline__ uint16_t f2bf(float f) {
    union { float f; uint32_t u; } v;
    v.f = f;
    uint32_t u = v.u;
    return (uint16_t)((u + 0x7fffu + ((u >> 16) & 1u)) >> 16);
}
__device__ __forceinline__ float bf2f(uint32_t b) {
    union { uint32_t u; float f; } v;
    v.u = b << 16;
    return v.f;
}

// Single cooperative kernel: CSR build + weight pack + x->bf16 cast +
// neighbor-mean gather + MFMA GEMM + LayerNorm + ReLU.
// Scratch layout inside d_out (each out row = 512 B):
//   [row*512 + 0, 256)   bf16 x row (written P4, read P5/P6)
//   [row*512 + 256, 512) bf16 neighbor-mean row (written P5, read P6)
// P6 overwrites each row with the final fp32 output (reads own rows first).
__global__ __launch_bounds__(256, 4) void k_all(
    const float* __restrict__ x, const int* __restrict__ ei,
    const float* __restrict__ wself, const float* __restrict__ wneigh,
    const float* __restrict__ bias, const float* __restrict__ gamma_,
    const float* __restrict__ beta_, float* out,
    int* deg, int* off, int* cur, int* adj, uint16_t* wpack) {
    cg::grid_group gg = cg::this_grid();
    __shared__ __align__(16) unsigned char smem[33792];  // As (bf16 frags) / Cs (fp32) / scan ps
    __shared__ float prm[3][128];

    int t = threadIdx.x;
    int bid = blockIdx.x;
    int nth = gridDim.x * 256;
    int tg = bid * 256 + t;
    unsigned char* scratch = (unsigned char*)out;

    // int64-vs-int32 edge_index probe (wave-uniform): odd words all zero <=> int64
    bool is64;
    {
        int w = ei[2 * (t & 63) + 1];
        is64 = (__ballot(w != 0) == 0ull);
    }

    // ---- P0: zero degrees ----
    for (int i = tg; i < N_; i += nth) deg[i] = 0;
    __threadfence();
    gg.sync();

    // ---- P1: degree count + weight prepack (B-fragment order) ----
    for (int e = tg; e < E_; e += nth) {
        int d = is64 ? ei[2 * (E_ + e)] : ei[E_ + e];
        atomicAdd(&deg[d], 1);
    }
    // B[k][n] = k<128 ? W_self[n][k] : W_neigh[n][k-128]
    for (int g = tg; g < 32768; g += nth) {
        int j = g & 7;
        int lane = (g >> 3) & 63;
        int nt2 = (g >> 9) & 7;
        int ks = g >> 12;
        int k = ks * 32 + (lane >> 4) * 8 + j;
        int n = nt2 * 16 + (lane & 15);
        float v = (k < 128) ? wself[n * 128 + k] : wneigh[n * 128 + (k - 128)];
        wpack[g] = f2bf(v);
    }
    __threadfence();
    gg.sync();

    // ---- P2: exclusive scan of degrees (block 0 only) ----
    if (bid == 0) {
        int* ps = (int*)smem;
        int base = t * 64;
        int s = 0;
        for (int i = 0; i < 64; i += 4) {
            int4 v = *(const int4*)(deg + base + i);
            s += v.x + v.y + v.z + v.w;
        }
        ps[t] = s;
        __syncthreads();
        for (int st = 1; st < 256; st <<= 1) {
            int add = (t >= st) ? ps[t - st] : 0;
            __syncthreads();
            ps[t] += add;
            __syncthreads();
        }
        int run = ps[t] - s;  // exclusive base
        for (int i = 0; i < 64; i += 4) {
            int4 v = *(const int4*)(deg + base + i);
            off[base + i] = run; cur[base + i] = run; run += v.x;
            off[base + i + 1] = run; cur[base + i + 1] = run; run += v.y;
            off[base + i + 2] = run; cur[base + i + 2] = run; run += v.z;
            off[base + i + 3] = run; cur[base + i + 3] = run; run += v.w;
        }
        if (t == 255) off[N_] = run;
    }
    __threadfence();
    gg.sync();

    // ---- P3: fill adjacency ----
    for (int e = tg; e < E_; e += nth) {
        int s = is64 ? ei[2 * e] : ei[e];
        int d = is64 ? ei[2 * (E_ + e)] : ei[E_ + e];
        int p = atomicAdd(&cur[d], 1);
        adj[p] = s;
    }
    __threadfence();
    gg.sync();

    // ---- P4: cast x fp32 -> bf16 rows into scratch[row*512 + 0..256) ----
    for (int gi = tg; gi < B_ * N_ * D_ / 4; gi += nth) {
        float4 v = ((const float4*)x)[gi];
        int row = gi >> 5, c4 = gi & 31;
        uint2 pv;
        pv.x = (uint32_t)f2bf(v.x) | ((uint32_t)f2bf(v.y) << 16);
        pv.y = (uint32_t)f2bf(v.z) | ((uint32_t)f2bf(v.w) << 16);
        *(uint2*)(scratch + (size_t)row * 512 + c4 * 8) = pv;
    }
    __threadfence();
    gg.sync();

    // ---- P5: neighbor mean, one 32-lane half-wave per (graph, node) ----
    {
        int l = t & 31;
        int hw = tg >> 5;
        int nhw = nth >> 5;
        for (int nid = hw; nid < B_ * N_; nid += nhw) {
            int g = nid & 15, node = nid >> 4;  // 16 consecutive half-waves share off/adj
            int o0 = off[node], o1 = off[node + 1];
            const unsigned char* xg = scratch + (size_t)g * N_ * 512;
            float a0 = 0.f, a1 = 0.f, a2 = 0.f, a3 = 0.f;
            int e = o0;
            for (; e + 1 < o1; e += 2) {
                int s0 = adj[e], s1 = adj[e + 1];
                uint2 v0 = *(const uint2*)(xg + (size_t)s0 * 512 + l * 8);
                uint2 v1 = *(const uint2*)(xg + (size_t)s1 * 512 + l * 8);
                a0 += bf2f(v0.x & 0xffffu) + bf2f(v1.x & 0xffffu);
                a1 += bf2f(v0.x >> 16) + bf2f(v1.x >> 16);
                a2 += bf2f(v0.y & 0xffffu) + bf2f(v1.y & 0xffffu);
                a3 += bf2f(v0.y >> 16) + bf2f(v1.y >> 16);
            }
            if (e < o1) {
                int s0 = adj[e];
                uint2 v0 = *(const uint2*)(xg + (size_t)s0 * 512 + l * 8);
                a0 += bf2f(v0.x & 0xffffu);
                a1 += bf2f(v0.x >> 16);
                a2 += bf2f(v0.y & 0xffffu);
                a3 += bf2f(v0.y >> 16);
            }
            float sc = 1.f / fmaxf((float)(o1 - o0), 1.f);
            uint2 pv;
            pv.x = (uint32_t)f2bf(a0 * sc) | ((uint32_t)f2bf(a1 * sc) << 16);
            pv.y = (uint32_t)f2bf(a2 * sc) | ((uint32_t)f2bf(a3 * sc) << 16);
            *(uint2*)(scratch + ((size_t)g * N_ + node) * 512 + 256 + l * 8) = pv;
        }
    }
    __threadfence();
    gg.sync();

    // ---- P6: MFMA GEMM + bias + LayerNorm + ReLU ----
    if (t < 128) {
        prm[0][t] = bias[t];
        prm[1][t] = gamma_[t];
        prm[2][t] = beta_[t];
    }
    uint16_t* As = (uint16_t*)smem;
    float* Cs = (float*)smem;
    int r = t >> 2;   // row in tile 0..63
    int q = t & 3;    // 32-dim quarter
    int wv = t >> 6, lane = t & 63;
    int mt = r >> 4, m = r & 15;

    for (int tid = bid; tid < NTILES; tid += gridDim.x) {
        int b = tid & 15, tile = tid >> 4;
        size_t row = (size_t)b * N_ + tile * 64 + r;

        // stage self (chunks 0..15) + nb (chunks 16..31) from one 512 B row
        const uint4* sv = (const uint4*)(scratch + row * 512);
#pragma unroll
        for (int c = 0; c < 4; c++) {
            uint4 v = sv[q * 4 + c];
            int kc = q * 4 + c, ks = kc >> 2, qd = kc & 3;
            *(uint4*)&As[(((ks * 4 + mt) * 64) + qd * 16 + m) * 8] = v;
        }
#pragma unroll
        for (int c = 0; c < 4; c++) {
            uint4 v = sv[16 + q * 4 + c];
            int kc = 16 + q * 4 + c, ks = kc >> 2, qd = kc & 3;
            *(uint4*)&As[(((ks * 4 + mt) * 64) + qd * 16 + m) * 8] = v;
        }
        __syncthreads();

        f32x4 accv[4][2];
#pragma unroll
        for (int i = 0; i < 4; i++)
#pragma unroll
            for (int j = 0; j < 2; j++) {
                f32x4 z = {0.f, 0.f, 0.f, 0.f};
                accv[i][j] = z;
            }
        const uint4* wp = (const uint4*)wpack;
#pragma unroll
        for (int ks = 0; ks < 8; ks++) {
            uint4 b0u = wp[(ks * 8 + 2 * wv + 0) * 64 + lane];
            uint4 b1u = wp[(ks * 8 + 2 * wv + 1) * 64 + lane];
            bf16x8 bf0 = __builtin_bit_cast(bf16x8, b0u);
            bf16x8 bf1 = __builtin_bit_cast(bf16x8, b1u);
#pragma unroll
            for (int mtt = 0; mtt < 4; mtt++) {
                bf16x8 a = *(const bf16x8*)&As[((ks * 4 + mtt) * 64 + lane) * 8];
                accv[mtt][0] = __builtin_amdgcn_mfma_f32_16x16x32_bf16(a, bf0, accv[mtt][0], 0, 0, 0);
                accv[mtt][1] = __builtin_amdgcn_mfma_f32_16x16x32_bf16(a, bf1, accv[mtt][1], 0, 0, 0);
            }
        }
        __syncthreads();  // As dead; reuse as Cs

        // C/D: row=(lane>>4)*4+reg (+mtt*16), col=lane&15 (+ntile*16)
#pragma unroll
        for (int mtt = 0; mtt < 4; mtt++)
#pragma unroll
            for (int ntl = 0; ntl < 2; ntl++)
#pragma unroll
                for (int rg = 0; rg < 4; rg++) {
                    int rr = mtt * 16 + (lane >> 4) * 4 + rg;
                    int cc = (2 * wv + ntl) * 16 + (lane & 15);
                    Cs[rr * 132 + (cc >> 5) * 33 + (cc & 31)] = accv[mtt][ntl][rg];
                }
        __syncthreads();

        float s1 = 0.f, s2 = 0.f;
#pragma unroll
        for (int i = 0; i < 32; i++) {
            float v = Cs[r * 132 + q * 33 + i] + prm[0][q * 32 + i];
            s1 += v;
            s2 += v * v;
        }
        s1 += __shfl_xor(s1, 1, 64);
        s2 += __shfl_xor(s2, 1, 64);
        s1 += __shfl_xor(s1, 2, 64);
        s2 += __shfl_xor(s2, 2, 64);
        float mu = s1 * (1.f / 128.f);
        float var = s2 * (1.f / 128.f) - mu * mu;
        float rstd = rsqrtf(var + 1e-5f);

        float* orow = out + row * (size_t)D_;
#pragma unroll
        for (int c = 0; c < 8; c++) {
            float tmp[4];
#pragma unroll
            for (int j = 0; j < 4; j++) {
                int i0 = c * 4 + j;
                int d0 = q * 32 + i0;
                float v = Cs[r * 132 + q * 33 + i0] + prm[0][d0];
                tmp[j] = fmaxf((v - mu) * rstd * prm[1][d0] + prm[2][d0], 0.f);
            }
            float4 o;
            o.x = tmp[0]; o.y = tmp[1]; o.z = tmp[2]; o.w = tmp[3];
            *(float4*)&orow[q * 32 + c * 4] = o;
        }
        __syncthreads();  // before next tile overwrites As
    }
}

extern "C" void kernel_launch(void* const* d_in, const int* in_sizes, int n_in,
                              void* d_out, int out_size, void* d_ws, size_t ws_size,
                              hipStream_t stream) {
    (void)in_sizes; (void)n_in; (void)out_size; (void)ws_size;
    const float* x      = (const float*)d_in[0];
    const int*   ei     = (const int*)d_in[1];
    // d_in[2] = batch_size (16), compile-time constant here
    const float* wself  = (const float*)d_in[3];
    const float* wneigh = (const float*)d_in[4];
    const float* bias   = (const float*)d_in[5];
    const float* gma    = (const float*)d_in[6];
    const float* bta    = (const float*)d_in[7];
    float* out = (float*)d_out;

    char* ws = (char*)d_ws;
    int* deg        = (int*)(ws);                 // 16384 ints   @0
    int* off        = (int*)(ws + 65536);         // 16385 ints   @65536
    int* cur        = (int*)(ws + 131584);        // 16384 ints   @131584
    int* adj        = (int*)(ws + 197120);        // 65536 ints   @197120
    uint16_t* wpack = (uint16_t*)(ws + 459264);   // 32768 bf16   @459264

    int maxB = 0;
    if (hipOccupancyMaxActiveBlocksPerMultiprocessor(&maxB, k_all, 256, 0) != hipSuccess ||
        maxB < 1)
        maxB = 2;  // conservative fallback: 512 blocks always co-resident
    int grid = 256 * maxB;
    if (grid > 1024) grid = 1024;

    void* args[] = {(void*)&x,   (void*)&ei,  (void*)&wself, (void*)&wneigh,
                    (void*)&bias, (void*)&gma, (void*)&bta,   (void*)&out,
                    (void*)&deg,  (void*)&off, (void*)&cur,   (void*)&adj,
                    (void*)&wpack};
    hipLaunchCooperativeKernel((const void*)k_all, dim3(grid), dim3(256), args, 0, stream);
}